// Round 1
// baseline (792.732 us; speedup 1.0000x reference)
//
#include <hip/hip_runtime.h>

#define W    768
#define PIX  (768*768)
#define NMAPS 16   // maps 0..7 = anno batches, 8..15 = pred-argmax batches

// ---------------- union-find (atomicMin root linking) ----------------

__device__ __forceinline__ int find_root(volatile int* L, int x) {
    int y = L[x];
    while (y != x) { x = y; y = L[x]; }
    return x;
}

__device__ __forceinline__ void unite(int* L, int a, int b) {
    volatile int* Lv = L;
    while (true) {
        a = find_root(Lv, a);
        b = find_root(Lv, b);
        if (a == b) return;
        if (a > b) { int t = a; a = b; b = t; }
        int old = atomicMin(&L[b], a);
        if (old == b) return;   // linked root b under a
        b = old;                // raced; follow the new parent and retry
    }
}

// ---------------- kernels ----------------

__global__ void zero_counts_k(int* counts) {
    int i = threadIdx.x;
    if (i < 32) counts[i] = 0;
}

// Builds class map (anno passthrough or pred argmax) and self-labels.
__global__ void init_k(const float* __restrict__ pred,
                       const int*   __restrict__ anno,
                       int* __restrict__ labels,
                       unsigned char* __restrict__ cls,
                       int m0) {
    int gid = blockIdx.x * 256 + threadIdx.x;
    int mc  = gid / PIX;            // map index within this chunk
    int p   = gid - mc * PIX;       // pixel within map
    int m   = m0 + mc;              // global map id
    unsigned char c;
    if (m < 8) {
        c = (unsigned char)anno[(size_t)m * PIX + p];
    } else {
        int b = m - 8;
        const float* pb = pred + (size_t)b * 4 * PIX + p;
        float v0 = pb[0];
        float v1 = pb[(size_t)PIX];
        float v2 = pb[(size_t)2 * PIX];
        float v3 = pb[(size_t)3 * PIX];
        int best = 0; float bv = v0;            // strict '>' => first-max, matches jnp.argmax
        if (v1 > bv) { bv = v1; best = 1; }
        if (v2 > bv) { bv = v2; best = 2; }
        if (v3 > bv) { bv = v3; best = 3; }
        c = (unsigned char)best;
    }
    cls[(size_t)mc * PIX + p]    = c;
    labels[(size_t)mc * PIX + p] = p;
}

// One pass over right/down edges; union same-class in-{2,3} neighbors.
__global__ void merge_k(int* __restrict__ labels,
                        const unsigned char* __restrict__ cls) {
    int gid = blockIdx.x * 256 + threadIdx.x;
    int mc  = gid / PIX;
    int p   = gid - mc * PIX;
    const unsigned char* C = cls + (size_t)mc * PIX;
    int* L = labels + (size_t)mc * PIX;
    unsigned char c = C[p];
    if (c != 2 && c != 3) return;
    if ((p % W) != (W - 1) && C[p + 1] == c) unite(L, p, p + 1);
    if (p + W < PIX        && C[p + W] == c) unite(L, p, p + W);
}

// Roots (label==self) per class, block-reduced then one atomic per class.
__global__ void count_k(const int* __restrict__ labels,
                        const unsigned char* __restrict__ cls,
                        int* counts, int m0) {
    __shared__ int s2, s3;
    if (threadIdx.x == 0) { s2 = 0; s3 = 0; }
    __syncthreads();
    int gid = blockIdx.x * 256 + threadIdx.x;
    int mc  = gid / PIX;
    int p   = gid - mc * PIX;
    unsigned char c = cls[(size_t)mc * PIX + p];
    int lab = labels[(size_t)mc * PIX + p];
    if ((c == 2 || c == 3) && lab == p) {
        if (c == 2) atomicAdd(&s2, 1); else atomicAdd(&s3, 1);
    }
    __syncthreads();
    if (threadIdx.x == 0) {
        int m = m0 + mc;
        if (s2) atomicAdd(&counts[m * 2 + 0], s2);
        if (s3) atomicAdd(&counts[m * 2 + 1], s3);
    }
}

__global__ void final_k(const int* __restrict__ counts, float* __restrict__ out) {
    float s = 0.0f;
    for (int b = 0; b < 8; ++b) {
        float a2 = (float)counts[b * 2 + 0];
        float a3 = (float)counts[b * 2 + 1];
        float p2 = (float)counts[(8 + b) * 2 + 0];
        float p3 = (float)counts[(8 + b) * 2 + 1];
        float t2 = 1.0f - 2.0f * fminf(p2, a2) / (a2 + p2);
        float t3 = 1.0f - 2.0f * fminf(p3, a3) / (a3 + p3);
        s += t2 + t3;
    }
    out[0] = 0.5f * s;
}

// ---------------- launch ----------------

extern "C" void kernel_launch(void* const* d_in, const int* in_sizes, int n_in,
                              void* d_out, int out_size, void* d_ws, size_t ws_size,
                              hipStream_t stream) {
    const float* pred = (const float*)d_in[0];   // (8,4,1,768,768) f32
    const int*   anno = (const int*)d_in[1];     // (8,1,768,768) i32
    float* out = (float*)d_out;

    int* counts = (int*)d_ws;                    // 32 ints, padded to 256 B
    char* base  = (char*)d_ws + 256;

    const size_t per_map = (size_t)PIX * 4 + (size_t)PIX;   // labels + cls
    size_t avail = (ws_size > 256) ? ws_size - 256 : 0;
    int K = (int)(avail / per_map);
    if (K > NMAPS) K = NMAPS;
    if (K < 1)     K = 1;    // best effort; needs ~3 MB min

    zero_counts_k<<<1, 64, 0, stream>>>(counts);

    for (int m0 = 0; m0 < NMAPS; m0 += K) {
        int nm = NMAPS - m0; if (nm > K) nm = K;
        int* labels        = (int*)base;
        unsigned char* cls = (unsigned char*)(base + (size_t)K * PIX * 4);
        dim3 grid(nm * (PIX / 256));
        init_k <<<grid, 256, 0, stream>>>(pred, anno, labels, cls, m0);
        merge_k<<<grid, 256, 0, stream>>>(labels, cls);
        count_k<<<grid, 256, 0, stream>>>(labels, cls, counts, m0);
    }
    final_k<<<1, 1, 0, stream>>>(counts, out);
}

// Round 2
// 198.832 us; speedup vs baseline: 3.9870x; 3.9870x over previous
//
#include <hip/hip_runtime.h>

#define W    768
#define PIX  (768*768)
#define NMAPS 16   // maps 0..7 = anno batches, 8..15 = pred-argmax batches
#define CB   144   // count blocks per map (PIX/CB = 4096 px per block)
#define CSLOT 16   // ints per counter slot (64 B) -> independent atomic lines

// ---------------- union-find (atomicMin root linking) ----------------

__device__ __forceinline__ int find_root(volatile int* L, int x) {
    int y = L[x];
    while (y != x) { x = y; y = L[x]; }
    return x;
}

__device__ __forceinline__ void unite(int* L, int a, int b) {
    volatile int* Lv = L;
    while (true) {
        a = find_root(Lv, a);
        b = find_root(Lv, b);
        if (a == b) return;
        if (a > b) { int t = a; a = b; b = t; }
        int old = atomicMin(&L[b], a);
        if (old == b) return;   // linked root b under a
        b = old;                // raced; follow the new parent and retry
    }
}

// ---------------- kernels ----------------

__global__ void zero_counts_k(int* counts) {
    int i = blockIdx.x * 256 + threadIdx.x;
    if (i < 32 * CSLOT) counts[i] = 0;
}

// Builds class map (anno passthrough or pred argmax) and self-labels.
__global__ void init_k(const float* __restrict__ pred,
                       const int*   __restrict__ anno,
                       int* __restrict__ labels,
                       unsigned char* __restrict__ cls,
                       int m0) {
    int gid = blockIdx.x * 256 + threadIdx.x;
    int mc  = gid / PIX;            // map index within this chunk
    int p   = gid - mc * PIX;       // pixel within map
    int m   = m0 + mc;              // global map id
    unsigned char c;
    if (m < 8) {
        c = (unsigned char)anno[(size_t)m * PIX + p];
    } else {
        int b = m - 8;
        const float* pb = pred + (size_t)b * 4 * PIX + p;
        float v0 = pb[0];
        float v1 = pb[(size_t)PIX];
        float v2 = pb[(size_t)2 * PIX];
        float v3 = pb[(size_t)3 * PIX];
        int best = 0; float bv = v0;            // strict '>' => first-max, matches jnp.argmax
        if (v1 > bv) { bv = v1; best = 1; }
        if (v2 > bv) { bv = v2; best = 2; }
        if (v3 > bv) { bv = v3; best = 3; }
        c = (unsigned char)best;
    }
    cls[(size_t)mc * PIX + p] = c;
    // labels of out-of-class pixels are never read (unions and root checks
    // touch in-class indices only) -> skip those writes
    if (c == 2 || c == 3) labels[(size_t)mc * PIX + p] = p;
}

// One pass over right/down edges; union same-class in-{2,3} neighbors.
__global__ void merge_k(int* __restrict__ labels,
                        const unsigned char* __restrict__ cls) {
    int gid = blockIdx.x * 256 + threadIdx.x;
    int mc  = gid / PIX;
    int p   = gid - mc * PIX;
    const unsigned char* C = cls + (size_t)mc * PIX;
    int* L = labels + (size_t)mc * PIX;
    unsigned char c = C[p];
    if (c != 2 && c != 3) return;
    if ((p % W) != (W - 1) && C[p + 1] == c) unite(L, p, p + 1);
    if (p + W < PIX        && C[p + W] == c) unite(L, p, p + W);
}

// Roots (label==self) per class; private counters -> wave shuffle reduce ->
// LDS combine -> ONE padded global atomic per (block, class).
__global__ void count_k(const int* __restrict__ labels,
                        const unsigned char* __restrict__ cls,
                        int* counts, int m0) {
    int mc = blockIdx.x / CB;
    int bl = blockIdx.x - mc * CB;
    const int per = PIX / CB;               // 4096
    int base = bl * per;
    const unsigned char* C = cls + (size_t)mc * PIX;
    const int* L = labels + (size_t)mc * PIX;

    int c2 = 0, c3 = 0;
    for (int i = threadIdx.x; i < per; i += 256) {
        int p = base + i;
        unsigned char c = C[p];
        if ((c == 2 || c == 3) && L[p] == p) {
            if (c == 2) c2++; else c3++;
        }
    }
    for (int off = 32; off; off >>= 1) {
        c2 += __shfl_down(c2, off, 64);
        c3 += __shfl_down(c3, off, 64);
    }
    __shared__ int s2[4], s3[4];
    int wid  = threadIdx.x >> 6;
    int lane = threadIdx.x & 63;
    if (lane == 0) { s2[wid] = c2; s3[wid] = c3; }
    __syncthreads();
    if (threadIdx.x == 0) {
        int t2 = s2[0] + s2[1] + s2[2] + s2[3];
        int t3 = s3[0] + s3[1] + s3[2] + s3[3];
        int m = m0 + mc;
        if (t2) atomicAdd(&counts[(m * 2 + 0) * CSLOT], t2);
        if (t3) atomicAdd(&counts[(m * 2 + 1) * CSLOT], t3);
    }
}

__global__ void final_k(const int* __restrict__ counts, float* __restrict__ out) {
    float s = 0.0f;
    for (int b = 0; b < 8; ++b) {
        float a2 = (float)counts[(b * 2 + 0) * CSLOT];
        float a3 = (float)counts[(b * 2 + 1) * CSLOT];
        float p2 = (float)counts[((8 + b) * 2 + 0) * CSLOT];
        float p3 = (float)counts[((8 + b) * 2 + 1) * CSLOT];
        float t2 = 1.0f - 2.0f * fminf(p2, a2) / (a2 + p2);
        float t3 = 1.0f - 2.0f * fminf(p3, a3) / (a3 + p3);
        s += t2 + t3;
    }
    out[0] = 0.5f * s;
}

// ---------------- launch ----------------

extern "C" void kernel_launch(void* const* d_in, const int* in_sizes, int n_in,
                              void* d_out, int out_size, void* d_ws, size_t ws_size,
                              hipStream_t stream) {
    const float* pred = (const float*)d_in[0];   // (8,4,1,768,768) f32
    const int*   anno = (const int*)d_in[1];     // (8,1,768,768) i32
    float* out = (float*)d_out;

    int* counts = (int*)d_ws;                    // 32*CSLOT ints = 2 KB
    char* base  = (char*)d_ws + 4096;

    const size_t per_map = (size_t)PIX * 4 + (size_t)PIX;   // labels + cls
    size_t avail = (ws_size > 4096) ? ws_size - 4096 : 0;
    int K = (int)(avail / per_map);
    if (K > NMAPS) K = NMAPS;
    if (K < 1)     K = 1;    // best effort; needs ~3 MB min

    zero_counts_k<<<2, 256, 0, stream>>>(counts);

    for (int m0 = 0; m0 < NMAPS; m0 += K) {
        int nm = NMAPS - m0; if (nm > K) nm = K;
        int* labels        = (int*)base;
        unsigned char* cls = (unsigned char*)(base + (size_t)K * PIX * 4);
        dim3 grid(nm * (PIX / 256));
        init_k <<<grid, 256, 0, stream>>>(pred, anno, labels, cls, m0);
        merge_k<<<grid, 256, 0, stream>>>(labels, cls);
        count_k<<<dim3(nm * CB), 256, 0, stream>>>(labels, cls, counts, m0);
    }
    final_k<<<1, 1, 0, stream>>>(counts, out);
}

// Round 4
// 146.604 us; speedup vs baseline: 5.4073x; 1.3562x over previous
//
#include <hip/hip_runtime.h>

#define W     768
#define PIX   (768*768)
#define NMAPS 16            // 0..7 anno, 8..15 pred-argmax
#define TROWS 16
#define TPX   (TROWS*W)     // 12288 px per tile
#define NT    (768/TROWS)   // 48 tiles per map
#define NB    (NT-1)        // 47 tile boundaries per map
#define CSLOT 16            // ints per counter slot (64 B line)

// ---------------- union-find helpers ----------------

__device__ __forceinline__ int find_root_g(volatile int* L, int x) {
    int y = L[x];
    while (y != x) { x = y; y = L[x]; }
    return x;
}

// Global unite; returns true iff a link event occurred (two roots merged).
// Parents only decrease -> forest stays acyclic; each index loses rootness
// at most once (at its winning atomicMin), so total link events == #merges.
__device__ __forceinline__ bool unite_g(int* L, int a, int b) {
    volatile int* Lv = L;
    while (true) {
        a = find_root_g(Lv, a);
        b = find_root_g(Lv, b);
        if (a == b) return false;
        if (a > b) { int t = a; a = b; b = t; }
        int old = atomicMin(&L[b], a);
        if (old == b) return true;
        b = old;
    }
}

__device__ __forceinline__ int find_root_l(volatile int* L, int x) {
    int y = L[x];
    while (y != x) { x = y; y = L[x]; }
    return x;
}

__device__ __forceinline__ void unite_l(int* L, int a, int b) {
    volatile int* Lv = L;
    while (true) {
        a = find_root_l(Lv, a);
        b = find_root_l(Lv, b);
        if (a == b) return;
        if (a > b) { int t = a; a = b; b = t; }
        int old = atomicMin(&L[b], a);
        if (old == b) return;
        b = old;
    }
}

// ---------------- kernels ----------------

__global__ void zero_counts_k(int* counts) {
    int i = blockIdx.x * 256 + threadIdx.x;
    if (i < 32 * CSLOT) counts[i] = 0;
}

// One block per (map, 16-row tile): decode cls (anno or pred argmax),
// CCL entirely in LDS, write compressed MAP-LOCAL labels + boundary-row cls,
// count local roots per class.
__global__ __launch_bounds__(256) void fused_k(const float* __restrict__ pred,
                                               const int*   __restrict__ anno,
                                               int* __restrict__ labels,
                                               unsigned char* __restrict__ bcls,
                                               int* __restrict__ counts, int m0) {
    __shared__ int lab[TPX];               // 48 KB
    __shared__ unsigned char lcls[TPX];    // 12 KB
    __shared__ int s2[4], s3[4];

    int mc  = blockIdx.x / NT;
    int t   = blockIdx.x - mc * NT;
    int m   = m0 + mc;
    int tid = threadIdx.x;

    // ---- phase 1: decode class map into LDS, init labels ----
    if (m < 8) {
        const int4* src = (const int4*)(anno + (size_t)m * PIX + (size_t)t * TPX);
        #pragma unroll
        for (int j = 0; j < TPX / 4 / 256; ++j) {       // 12 iters
            int idx = j * 256 + tid;
            int4 v = src[idx];
            int i = idx * 4;
            lcls[i + 0] = (unsigned char)v.x;
            lcls[i + 1] = (unsigned char)v.y;
            lcls[i + 2] = (unsigned char)v.z;
            lcls[i + 3] = (unsigned char)v.w;
            lab[i + 0] = i + 0; lab[i + 1] = i + 1;
            lab[i + 2] = i + 2; lab[i + 3] = i + 3;
        }
    } else {
        const float4* p0 = (const float4*)(pred + (size_t)(m - 8) * 4 * PIX + (size_t)t * TPX);
        const int CH = PIX / 4;                          // channel stride in float4
        #pragma unroll
        for (int j = 0; j < TPX / 4 / 256; ++j) {
            int idx = j * 256 + tid;
            float4 v0 = p0[idx];
            float4 v1 = p0[CH + idx];
            float4 v2 = p0[2 * CH + idx];
            float4 v3 = p0[3 * CH + idx];
            int i = idx * 4;
            {   float bv = v0.x; int bi = 0;
                if (v1.x > bv) { bv = v1.x; bi = 1; }
                if (v2.x > bv) { bv = v2.x; bi = 2; }
                if (v3.x > bv) { bv = v3.x; bi = 3; }
                lcls[i + 0] = (unsigned char)bi; }
            {   float bv = v0.y; int bi = 0;
                if (v1.y > bv) { bv = v1.y; bi = 1; }
                if (v2.y > bv) { bv = v2.y; bi = 2; }
                if (v3.y > bv) { bv = v3.y; bi = 3; }
                lcls[i + 1] = (unsigned char)bi; }
            {   float bv = v0.z; int bi = 0;
                if (v1.z > bv) { bv = v1.z; bi = 1; }
                if (v2.z > bv) { bv = v2.z; bi = 2; }
                if (v3.z > bv) { bv = v3.z; bi = 3; }
                lcls[i + 2] = (unsigned char)bi; }
            {   float bv = v0.w; int bi = 0;
                if (v1.w > bv) { bv = v1.w; bi = 1; }
                if (v2.w > bv) { bv = v2.w; bi = 2; }
                if (v3.w > bv) { bv = v3.w; bi = 3; }
                lcls[i + 3] = (unsigned char)bi; }
            lab[i + 0] = i + 0; lab[i + 1] = i + 1;
            lab[i + 2] = i + 2; lab[i + 3] = i + 3;
        }
    }
    __syncthreads();

    // ---- phase 2: union right/down edges within tile (LDS atomics) ----
    for (int px = tid; px < TPX; px += 256) {
        unsigned char c = lcls[px];
        if (c == 2 || c == 3) {
            int row = px / W;
            int col = px - row * W;
            if (col != W - 1 && lcls[px + 1] == c) unite_l(lab, px, px + 1);
            if (px + W < TPX  && lcls[px + W] == c) unite_l(lab, px, px + W);
        }
    }
    __syncthreads();

    // ---- phase 3: resolve roots, count, write compressed labels ----
    // label VALUES are map-local (lbase + r), matching boundary_k's per-map
    // base pointer; only the store ADDRESS uses the chunk offset mc*PIX.
    int c2 = 0, c3 = 0;
    int lbase = t * TPX;                       // map-local base of this tile
    int gbase = mc * PIX + lbase;              // chunk-local store base
    #pragma unroll
    for (int j = 0; j < TPX / 4 / 256; ++j) {
        int idx = j * 256 + tid;
        int i = idx * 4;
        int vv[4];
        #pragma unroll
        for (int q = 0; q < 4; ++q) {
            int px = i + q;
            unsigned char c = lcls[px];
            int r = px;
            if (c == 2 || c == 3) {
                r = find_root_l(lab, px);
                if (r == px) { if (c == 2) c2++; else c3++; }
            }
            vv[q] = lbase + r;
        }
        ((int4*)labels)[gbase / 4 + idx] = make_int4(vv[0], vv[1], vv[2], vv[3]);
    }
    // boundary-row cls (tile rows 0 and TROWS-1) into compact array
    for (int px = tid; px < W; px += 256) {
        size_t bb = ((size_t)(mc * NT + t) * 2) * W;
        bcls[bb + px]     = lcls[px];
        bcls[bb + W + px] = lcls[TPX - W + px];
    }
    // reduce root counts -> one padded atomic per (block, class)
    for (int off = 32; off; off >>= 1) {
        c2 += __shfl_down(c2, off, 64);
        c3 += __shfl_down(c3, off, 64);
    }
    int wid = tid >> 6, lane = tid & 63;
    if (lane == 0) { s2[wid] = c2; s3[wid] = c3; }
    __syncthreads();
    if (tid == 0) {
        int t2 = s2[0] + s2[1] + s2[2] + s2[3];
        int t3 = s3[0] + s3[1] + s3[2] + s3[3];
        if (t2) atomicAdd(&counts[(m * 2 + 0) * CSLOT], t2);
        if (t3) atomicAdd(&counts[(m * 2 + 1) * CSLOT], t3);
    }
}

// Cross-tile boundary edges: union in global labels; each successful
// root-link decrements that class's component count by exactly 1.
__global__ __launch_bounds__(256) void boundary_k(int* __restrict__ labels,
                                                  const unsigned char* __restrict__ bcls,
                                                  int* __restrict__ counts, int m0) {
    __shared__ int s2[4], s3[4];
    const int PERMAP = NB * W;                 // 36096 = 141 * 256 exactly
    int gid = blockIdx.x * 256 + threadIdx.x;
    int mc  = gid / PERMAP;
    int i   = gid - mc * PERMAP;
    int b   = i / W;
    int col = i - b * W;
    int m   = m0 + mc;

    int m2 = 0, m3 = 0;
    unsigned char cA = bcls[((size_t)(mc * NT + b) * 2 + 1) * W + col];      // tile b, row 15
    unsigned char cB = bcls[((size_t)(mc * NT + b + 1) * 2 + 0) * W + col];  // tile b+1, row 0
    if (cA == cB && (cA == 2 || cA == 3)) {
        int* L = labels + (size_t)mc * PIX;
        int p1 = b * TPX + (TROWS - 1) * W + col;
        int p2 = p1 + W;
        if (unite_g(L, p1, p2)) { if (cA == 2) m2++; else m3++; }
    }
    for (int off = 32; off; off >>= 1) {
        m2 += __shfl_down(m2, off, 64);
        m3 += __shfl_down(m3, off, 64);
    }
    int wid = threadIdx.x >> 6, lane = threadIdx.x & 63;
    if (lane == 0) { s2[wid] = m2; s3[wid] = m3; }
    __syncthreads();
    if (threadIdx.x == 0) {
        int t2 = s2[0] + s2[1] + s2[2] + s2[3];
        int t3 = s3[0] + s3[1] + s3[2] + s3[3];
        if (t2) atomicSub(&counts[(m * 2 + 0) * CSLOT], t2);
        if (t3) atomicSub(&counts[(m * 2 + 1) * CSLOT], t3);
    }
}

__global__ void final_k(const int* __restrict__ counts, float* __restrict__ out) {
    float s = 0.0f;
    for (int b = 0; b < 8; ++b) {
        float a2 = (float)counts[(b * 2 + 0) * CSLOT];
        float a3 = (float)counts[(b * 2 + 1) * CSLOT];
        float p2 = (float)counts[((8 + b) * 2 + 0) * CSLOT];
        float p3 = (float)counts[((8 + b) * 2 + 1) * CSLOT];
        float t2 = 1.0f - 2.0f * fminf(p2, a2) / (a2 + p2);
        float t3 = 1.0f - 2.0f * fminf(p3, a3) / (a3 + p3);
        s += t2 + t3;
    }
    out[0] = 0.5f * s;
}

// ---------------- launch ----------------

extern "C" void kernel_launch(void* const* d_in, const int* in_sizes, int n_in,
                              void* d_out, int out_size, void* d_ws, size_t ws_size,
                              hipStream_t stream) {
    const float* pred = (const float*)d_in[0];   // (8,4,1,768,768) f32
    const int*   anno = (const int*)d_in[1];     // (8,1,768,768) i32
    float* out = (float*)d_out;

    int* counts = (int*)d_ws;                    // 32*CSLOT ints = 2 KB
    char* base  = (char*)d_ws + 4096;

    const size_t per_map = (size_t)PIX * 4 + (size_t)NT * 2 * W;  // labels + bcls
    size_t avail = (ws_size > 4096) ? ws_size - 4096 : 0;
    int K = (int)(avail / per_map);
    if (K > NMAPS) K = NMAPS;
    if (K < 1)     K = 1;    // best effort; needs ~2.4 MB min

    zero_counts_k<<<2, 256, 0, stream>>>(counts);

    for (int m0 = 0; m0 < NMAPS; m0 += K) {
        int nm = NMAPS - m0; if (nm > K) nm = K;
        int* labels        = (int*)base;
        unsigned char* bcls = (unsigned char*)(base + (size_t)K * PIX * 4);
        fused_k   <<<dim3(nm * NT), 256, 0, stream>>>(pred, anno, labels, bcls, counts, m0);
        boundary_k<<<dim3(nm * (NB * W / 256)), 256, 0, stream>>>(labels, bcls, counts, m0);
    }
    final_k<<<1, 1, 0, stream>>>(counts, out);
}

// Round 5
// 99.312 us; speedup vs baseline: 7.9822x; 1.4762x over previous
//
#include <hip/hip_runtime.h>

#define W     768
#define PIX   (768*768)
#define NMAPS 16            // 0..7 anno, 8..15 pred-argmax
#define TROWS 8
#define TPX   (TROWS*W)     // 6144 px per tile
#define NT    (768/TROWS)   // 96 tiles per map
#define NB    (NT-1)        // 95 tile boundaries per map
#define CSLOT 16            // ints per counter slot (64 B line)

// ---------------- union-find helpers ----------------

__device__ __forceinline__ int find_root_g(volatile int* L, int x) {
    int y = L[x];
    while (y != x) { x = y; y = L[x]; }
    return x;
}

// Global unite; returns true iff a link event occurred (two roots merged).
// Parents only decrease -> forest stays acyclic; each index loses rootness
// at most once (at its winning atomicMin), so total link events == #merges.
__device__ __forceinline__ bool unite_g(int* L, int a, int b) {
    volatile int* Lv = L;
    while (true) {
        a = find_root_g(Lv, a);
        b = find_root_g(Lv, b);
        if (a == b) return false;
        if (a > b) { int t = a; a = b; b = t; }
        int old = atomicMin(&L[b], a);
        if (old == b) return true;
        b = old;
    }
}

__device__ __forceinline__ int find_root_l(volatile int* L, int x) {
    int y = L[x];
    while (y != x) { x = y; y = L[x]; }
    return x;
}

__device__ __forceinline__ void unite_l(int* L, int a, int b) {
    volatile int* Lv = L;
    while (true) {
        a = find_root_l(Lv, a);
        b = find_root_l(Lv, b);
        if (a == b) return;
        if (a > b) { int t = a; a = b; b = t; }
        int old = atomicMin(&L[b], a);
        if (old == b) return;
        b = old;
    }
}

// ---------------- kernels ----------------

__global__ void zero_counts_k(int* counts) {
    int i = blockIdx.x * 256 + threadIdx.x;
    if (i < 32 * CSLOT) counts[i] = 0;
}

// One block per (map, 8-row tile): decode cls (anno or pred argmax),
// CCL entirely in LDS, write compressed MAP-LOCAL labels + boundary-row cls,
// count local roots per class.
__global__ __launch_bounds__(256) void fused_k(const float* __restrict__ pred,
                                               const int*   __restrict__ anno,
                                               int* __restrict__ labels,
                                               unsigned char* __restrict__ bcls,
                                               int* __restrict__ counts, int m0) {
    __shared__ int lab[TPX];               // 24 KB
    __shared__ unsigned char lcls[TPX];    //  6 KB
    __shared__ int s2[4], s3[4];

    int mc  = blockIdx.x / NT;
    int t   = blockIdx.x - mc * NT;
    int m   = m0 + mc;
    int tid = threadIdx.x;

    // ---- phase 1: decode class map into LDS, init labels ----
    if (m < 8) {
        const int4* src = (const int4*)(anno + (size_t)m * PIX + (size_t)t * TPX);
        #pragma unroll
        for (int j = 0; j < TPX / 4 / 256; ++j) {       // 6 iters
            int idx = j * 256 + tid;
            int4 v = src[idx];
            int i = idx * 4;
            *(unsigned int*)&lcls[i] =
                (unsigned int)(v.x & 0xff) | ((unsigned int)(v.y & 0xff) << 8) |
                ((unsigned int)(v.z & 0xff) << 16) | ((unsigned int)(v.w & 0xff) << 24);
            lab[i + 0] = i + 0; lab[i + 1] = i + 1;
            lab[i + 2] = i + 2; lab[i + 3] = i + 3;
        }
    } else {
        const float4* p0 = (const float4*)(pred + (size_t)(m - 8) * 4 * PIX + (size_t)t * TPX);
        const int CH = PIX / 4;                          // channel stride in float4
        #pragma unroll
        for (int j = 0; j < TPX / 4 / 256; ++j) {
            int idx = j * 256 + tid;
            float4 v0 = p0[idx];
            float4 v1 = p0[CH + idx];
            float4 v2 = p0[2 * CH + idx];
            float4 v3 = p0[3 * CH + idx];
            int i = idx * 4;
            unsigned int pk;
            {   float bv = v0.x; int bi = 0;
                if (v1.x > bv) { bv = v1.x; bi = 1; }
                if (v2.x > bv) { bv = v2.x; bi = 2; }
                if (v3.x > bv) { bv = v3.x; bi = 3; }
                pk = (unsigned int)bi; }
            {   float bv = v0.y; int bi = 0;
                if (v1.y > bv) { bv = v1.y; bi = 1; }
                if (v2.y > bv) { bv = v2.y; bi = 2; }
                if (v3.y > bv) { bv = v3.y; bi = 3; }
                pk |= (unsigned int)bi << 8; }
            {   float bv = v0.z; int bi = 0;
                if (v1.z > bv) { bv = v1.z; bi = 1; }
                if (v2.z > bv) { bv = v2.z; bi = 2; }
                if (v3.z > bv) { bv = v3.z; bi = 3; }
                pk |= (unsigned int)bi << 16; }
            {   float bv = v0.w; int bi = 0;
                if (v1.w > bv) { bv = v1.w; bi = 1; }
                if (v2.w > bv) { bv = v2.w; bi = 2; }
                if (v3.w > bv) { bv = v3.w; bi = 3; }
                pk |= (unsigned int)bi << 24; }
            *(unsigned int*)&lcls[i] = pk;
            lab[i + 0] = i + 0; lab[i + 1] = i + 1;
            lab[i + 2] = i + 2; lab[i + 3] = i + 3;
        }
    }
    __syncthreads();

    // ---- phase 2: union right/down edges within tile (LDS atomics) ----
    for (int px = tid; px < TPX; px += 256) {
        unsigned char c = lcls[px];
        if (c == 2 || c == 3) {
            int row = px / W;
            int col = px - row * W;
            if (col != W - 1 && lcls[px + 1] == c) unite_l(lab, px, px + 1);
            if (px + W < TPX  && lcls[px + W] == c) unite_l(lab, px, px + W);
        }
    }
    __syncthreads();

    // ---- phase 3: resolve roots, count, write compressed labels ----
    // label VALUES are map-local (lbase + r); store ADDRESS uses mc*PIX.
    int c2 = 0, c3 = 0;
    int lbase = t * TPX;                       // map-local base of this tile
    int gbase = mc * PIX + lbase;              // chunk-local store base
    #pragma unroll
    for (int j = 0; j < TPX / 4 / 256; ++j) {
        int idx = j * 256 + tid;
        int i = idx * 4;
        int vv[4];
        #pragma unroll
        for (int q = 0; q < 4; ++q) {
            int px = i + q;
            unsigned char c = lcls[px];
            int r = px;
            if (c == 2 || c == 3) {
                r = find_root_l(lab, px);
                if (r == px) { if (c == 2) c2++; else c3++; }
            }
            vv[q] = lbase + r;
        }
        ((int4*)labels)[gbase / 4 + idx] = make_int4(vv[0], vv[1], vv[2], vv[3]);
    }
    // boundary-row cls (tile rows 0 and TROWS-1) into compact array
    for (int px = tid; px < W; px += 256) {
        size_t bb = ((size_t)(mc * NT + t) * 2) * W;
        bcls[bb + px]     = lcls[px];
        bcls[bb + W + px] = lcls[TPX - W + px];
    }
    // reduce root counts -> one padded atomic per (block, class)
    for (int off = 32; off; off >>= 1) {
        c2 += __shfl_down(c2, off, 64);
        c3 += __shfl_down(c3, off, 64);
    }
    int wid = tid >> 6, lane = tid & 63;
    if (lane == 0) { s2[wid] = c2; s3[wid] = c3; }
    __syncthreads();
    if (tid == 0) {
        int t2 = s2[0] + s2[1] + s2[2] + s2[3];
        int t3 = s3[0] + s3[1] + s3[2] + s3[3];
        if (t2) atomicAdd(&counts[(m * 2 + 0) * CSLOT], t2);
        if (t3) atomicAdd(&counts[(m * 2 + 1) * CSLOT], t3);
    }
}

// Cross-tile boundary edges: union in global labels; each successful
// root-link decrements that class's component count by exactly 1.
__global__ __launch_bounds__(256) void boundary_k(int* __restrict__ labels,
                                                  const unsigned char* __restrict__ bcls,
                                                  int* __restrict__ counts, int m0) {
    __shared__ int s2[4], s3[4];
    const int PERMAP = NB * W;                 // 72960 = 285 * 256 exactly
    int gid = blockIdx.x * 256 + threadIdx.x;
    int mc  = gid / PERMAP;
    int i   = gid - mc * PERMAP;
    int b   = i / W;
    int col = i - b * W;
    int m   = m0 + mc;

    int m2 = 0, m3 = 0;
    unsigned char cA = bcls[((size_t)(mc * NT + b) * 2 + 1) * W + col];      // tile b, last row
    unsigned char cB = bcls[((size_t)(mc * NT + b + 1) * 2 + 0) * W + col];  // tile b+1, row 0
    if (cA == cB && (cA == 2 || cA == 3)) {
        int* L = labels + (size_t)mc * PIX;
        int p1 = b * TPX + (TROWS - 1) * W + col;
        int p2 = p1 + W;
        if (unite_g(L, p1, p2)) { if (cA == 2) m2++; else m3++; }
    }
    for (int off = 32; off; off >>= 1) {
        m2 += __shfl_down(m2, off, 64);
        m3 += __shfl_down(m3, off, 64);
    }
    int wid = threadIdx.x >> 6, lane = threadIdx.x & 63;
    if (lane == 0) { s2[wid] = m2; s3[wid] = m3; }
    __syncthreads();
    if (threadIdx.x == 0) {
        int t2 = s2[0] + s2[1] + s2[2] + s2[3];
        int t3 = s3[0] + s3[1] + s3[2] + s3[3];
        if (t2) atomicSub(&counts[(m * 2 + 0) * CSLOT], t2);
        if (t3) atomicSub(&counts[(m * 2 + 1) * CSLOT], t3);
    }
}

__global__ void final_k(const int* __restrict__ counts, float* __restrict__ out) {
    float s = 0.0f;
    for (int b = 0; b < 8; ++b) {
        float a2 = (float)counts[(b * 2 + 0) * CSLOT];
        float a3 = (float)counts[(b * 2 + 1) * CSLOT];
        float p2 = (float)counts[((8 + b) * 2 + 0) * CSLOT];
        float p3 = (float)counts[((8 + b) * 2 + 1) * CSLOT];
        float t2 = 1.0f - 2.0f * fminf(p2, a2) / (a2 + p2);
        float t3 = 1.0f - 2.0f * fminf(p3, a3) / (a3 + p3);
        s += t2 + t3;
    }
    out[0] = 0.5f * s;
}

// ---------------- launch ----------------

extern "C" void kernel_launch(void* const* d_in, const int* in_sizes, int n_in,
                              void* d_out, int out_size, void* d_ws, size_t ws_size,
                              hipStream_t stream) {
    const float* pred = (const float*)d_in[0];   // (8,4,1,768,768) f32
    const int*   anno = (const int*)d_in[1];     // (8,1,768,768) i32
    float* out = (float*)d_out;

    int* counts = (int*)d_ws;                    // 32*CSLOT ints = 2 KB
    char* base  = (char*)d_ws + 4096;

    const size_t per_map = (size_t)PIX * 4 + (size_t)NT * 2 * W;  // labels + bcls
    size_t avail = (ws_size > 4096) ? ws_size - 4096 : 0;
    int K = (int)(avail / per_map);
    if (K > NMAPS) K = NMAPS;
    if (K < 1)     K = 1;    // best effort; needs ~2.5 MB min

    zero_counts_k<<<2, 256, 0, stream>>>(counts);

    for (int m0 = 0; m0 < NMAPS; m0 += K) {
        int nm = NMAPS - m0; if (nm > K) nm = K;
        int* labels         = (int*)base;
        unsigned char* bcls = (unsigned char*)(base + (size_t)K * PIX * 4);
        fused_k   <<<dim3(nm * NT), 256, 0, stream>>>(pred, anno, labels, bcls, counts, m0);
        boundary_k<<<dim3(nm * (NB * W / 256)), 256, 0, stream>>>(labels, bcls, counts, m0);
    }
    final_k<<<1, 1, 0, stream>>>(counts, out);
}

// Round 6
// 83.909 us; speedup vs baseline: 9.4476x; 1.1836x over previous
//
#include <hip/hip_runtime.h>

#define W     768
#define PIX   (768*768)
#define NMAPS 16            // 0..7 anno, 8..15 pred-argmax
#define TROWS 6
#define TPX   (TROWS*W)     // 4608 px per tile
#define NT    (768/TROWS)   // 128 tiles per map
#define NB    (NT-1)        // 127 tile boundaries per map
#define CSLOT 16            // ints per counter slot (64 B line)

// ---------------- union-find helpers ----------------
// LDS entries are PACKED: (label<<2) | cls. Within a component all pixels
// share cls, and min over packed == min over label -> cls bits are invariant
// under atomicMin unions. One array serves labels AND class map.

__device__ __forceinline__ int find_root_p(volatile int* L, int x) {
    int y = L[x] >> 2;
    while (y != x) { x = y; y = L[x] >> 2; }
    return x;
}

__device__ __forceinline__ void unite_p(int* L, int a, int b, int c) {
    volatile int* Lv = L;
    while (true) {
        a = find_root_p(Lv, a);
        b = find_root_p(Lv, b);
        if (a == b) return;
        if (a > b) { int t = a; a = b; b = t; }
        int old = atomicMin(&L[b], (a << 2) | c);
        if ((old >> 2) == b) return;
        b = old >> 2;
    }
}

// Global (unpacked) union-find for cross-tile merging.
__device__ __forceinline__ int find_root_g(volatile int* L, int x) {
    int y = L[x];
    while (y != x) { x = y; y = L[x]; }
    return x;
}

// Returns true iff a link event occurred (two roots merged). Parents only
// decrease -> acyclic; each index loses rootness at most once, so
// #link events == #merges exactly, independent of atomic ordering.
__device__ __forceinline__ bool unite_g(int* L, int a, int b) {
    volatile int* Lv = L;
    while (true) {
        a = find_root_g(Lv, a);
        b = find_root_g(Lv, b);
        if (a == b) return false;
        if (a > b) { int t = a; a = b; b = t; }
        int old = atomicMin(&L[b], a);
        if (old == b) return true;
        b = old;
    }
}

// ---------------- kernels ----------------

__global__ void zero_counts_k(int* counts) {
    int i = blockIdx.x * 256 + threadIdx.x;
    if (i < 32 * CSLOT) counts[i] = 0;
}

// One block per (map, 6-row tile): decode cls (anno or pred argmax),
// CCL entirely in LDS (packed labels), write compressed MAP-LOCAL labels +
// boundary-row cls, count local roots per class.
__global__ __launch_bounds__(256) void fused_k(const float* __restrict__ pred,
                                               const int*   __restrict__ anno,
                                               int* __restrict__ labels,
                                               unsigned char* __restrict__ bcls,
                                               int* __restrict__ counts, int m0) {
    __shared__ int lab[TPX];               // 18 KB packed (label<<2)|cls
    __shared__ int s2[4], s3[4];

    int mc  = blockIdx.x / NT;
    int t   = blockIdx.x - mc * NT;
    int m   = m0 + mc;
    int tid = threadIdx.x;

    // ---- phase 1: decode class, init packed labels ----
    if (m < 8) {
        const int4* src = (const int4*)(anno + (size_t)m * PIX + (size_t)t * TPX);
        for (int idx = tid; idx < TPX / 4; idx += 256) {    // 1152 int4s
            int4 v = src[idx];
            int i = idx * 4;
            lab[i + 0] = ((i + 0) << 2) | (v.x & 3);
            lab[i + 1] = ((i + 1) << 2) | (v.y & 3);
            lab[i + 2] = ((i + 2) << 2) | (v.z & 3);
            lab[i + 3] = ((i + 3) << 2) | (v.w & 3);
        }
    } else {
        const float4* p0 = (const float4*)(pred + (size_t)(m - 8) * 4 * PIX + (size_t)t * TPX);
        const int CH = PIX / 4;                              // channel stride in float4
        for (int idx = tid; idx < TPX / 4; idx += 256) {
            float4 v0 = p0[idx];
            float4 v1 = p0[CH + idx];
            float4 v2 = p0[2 * CH + idx];
            float4 v3 = p0[3 * CH + idx];
            int i = idx * 4;
            {   float bv = v0.x; int bi = 0;
                if (v1.x > bv) { bv = v1.x; bi = 1; }
                if (v2.x > bv) { bv = v2.x; bi = 2; }
                if (v3.x > bv) { bv = v3.x; bi = 3; }
                lab[i + 0] = ((i + 0) << 2) | bi; }
            {   float bv = v0.y; int bi = 0;
                if (v1.y > bv) { bv = v1.y; bi = 1; }
                if (v2.y > bv) { bv = v2.y; bi = 2; }
                if (v3.y > bv) { bv = v3.y; bi = 3; }
                lab[i + 1] = ((i + 1) << 2) | bi; }
            {   float bv = v0.z; int bi = 0;
                if (v1.z > bv) { bv = v1.z; bi = 1; }
                if (v2.z > bv) { bv = v2.z; bi = 2; }
                if (v3.z > bv) { bv = v3.z; bi = 3; }
                lab[i + 2] = ((i + 2) << 2) | bi; }
            {   float bv = v0.w; int bi = 0;
                if (v1.w > bv) { bv = v1.w; bi = 1; }
                if (v2.w > bv) { bv = v2.w; bi = 2; }
                if (v3.w > bv) { bv = v3.w; bi = 3; }
                lab[i + 3] = ((i + 3) << 2) | bi; }
        }
    }
    __syncthreads();

    // ---- phase 2: union right/down edges (cls bits are stable) ----
    for (int px = tid; px < TPX; px += 256) {
        int c = lab[px] & 3;
        if (c & 2) {                                  // class 2 or 3
            int col = px % W;
            if (col != W - 1 && (lab[px + 1] & 3) == c) unite_p(lab, px, px + 1, c);
            if (px + W < TPX  && (lab[px + W] & 3) == c) unite_p(lab, px, px + W, c);
        }
    }
    __syncthreads();

    // ---- phase 3: resolve roots, count, write compressed labels ----
    // label VALUES are map-local (lbase + r); store ADDRESS uses mc*PIX.
    int c2 = 0, c3 = 0;
    int lbase = t * TPX;
    int gbase = mc * PIX + lbase;
    for (int idx = tid; idx < TPX / 4; idx += 256) {
        int i = idx * 4;
        int vv[4];
        #pragma unroll
        for (int q = 0; q < 4; ++q) {
            int px = i + q;
            int c = lab[px] & 3;
            int r = px;
            if (c & 2) {
                r = find_root_p(lab, px);
                if (r == px) { if (c == 2) c2++; else c3++; }
            }
            vv[q] = lbase + r;
        }
        ((int4*)labels)[gbase / 4 + idx] = make_int4(vv[0], vv[1], vv[2], vv[3]);
    }
    // boundary-row cls (tile rows 0 and TROWS-1) into compact array
    for (int px = tid; px < W; px += 256) {
        size_t bb = ((size_t)(mc * NT + t) * 2) * W;
        bcls[bb + px]     = (unsigned char)(lab[px] & 3);
        bcls[bb + W + px] = (unsigned char)(lab[TPX - W + px] & 3);
    }
    // reduce root counts -> one padded atomic per (block, class)
    for (int off = 32; off; off >>= 1) {
        c2 += __shfl_down(c2, off, 64);
        c3 += __shfl_down(c3, off, 64);
    }
    int wid = tid >> 6, lane = tid & 63;
    if (lane == 0) { s2[wid] = c2; s3[wid] = c3; }
    __syncthreads();
    if (tid == 0) {
        int t2 = s2[0] + s2[1] + s2[2] + s2[3];
        int t3 = s3[0] + s3[1] + s3[2] + s3[3];
        if (t2) atomicAdd(&counts[(m * 2 + 0) * CSLOT], t2);
        if (t3) atomicAdd(&counts[(m * 2 + 1) * CSLOT], t3);
    }
}

// Cross-tile boundary edges: union in global labels; each successful
// root-link decrements that class's component count by exactly 1.
__global__ __launch_bounds__(256) void boundary_k(int* __restrict__ labels,
                                                  const unsigned char* __restrict__ bcls,
                                                  int* __restrict__ counts, int m0) {
    __shared__ int s2[4], s3[4];
    const int PERMAP = NB * W;                 // 97536 = 381 * 256 exactly
    int gid = blockIdx.x * 256 + threadIdx.x;
    int mc  = gid / PERMAP;
    int i   = gid - mc * PERMAP;
    int b   = i / W;
    int col = i - b * W;
    int m   = m0 + mc;

    int m2 = 0, m3 = 0;
    unsigned char cA = bcls[((size_t)(mc * NT + b) * 2 + 1) * W + col];      // tile b, last row
    unsigned char cB = bcls[((size_t)(mc * NT + b + 1) * 2 + 0) * W + col];  // tile b+1, row 0
    if (cA == cB && (cA & 2)) {
        int* L = labels + (size_t)mc * PIX;
        int p1 = b * TPX + (TROWS - 1) * W + col;
        int p2 = p1 + W;
        if (unite_g(L, p1, p2)) { if (cA == 2) m2++; else m3++; }
    }
    for (int off = 32; off; off >>= 1) {
        m2 += __shfl_down(m2, off, 64);
        m3 += __shfl_down(m3, off, 64);
    }
    int wid = threadIdx.x >> 6, lane = threadIdx.x & 63;
    if (lane == 0) { s2[wid] = m2; s3[wid] = m3; }
    __syncthreads();
    if (threadIdx.x == 0) {
        int t2 = s2[0] + s2[1] + s2[2] + s2[3];
        int t3 = s3[0] + s3[1] + s3[2] + s3[3];
        if (t2) atomicSub(&counts[(m * 2 + 0) * CSLOT], t2);
        if (t3) atomicSub(&counts[(m * 2 + 1) * CSLOT], t3);
    }
}

__global__ void final_k(const int* __restrict__ counts, float* __restrict__ out) {
    float s = 0.0f;
    for (int b = 0; b < 8; ++b) {
        float a2 = (float)counts[(b * 2 + 0) * CSLOT];
        float a3 = (float)counts[(b * 2 + 1) * CSLOT];
        float p2 = (float)counts[((8 + b) * 2 + 0) * CSLOT];
        float p3 = (float)counts[((8 + b) * 2 + 1) * CSLOT];
        float t2 = 1.0f - 2.0f * fminf(p2, a2) / (a2 + p2);
        float t3 = 1.0f - 2.0f * fminf(p3, a3) / (a3 + p3);
        s += t2 + t3;
    }
    out[0] = 0.5f * s;
}

// ---------------- launch ----------------

extern "C" void kernel_launch(void* const* d_in, const int* in_sizes, int n_in,
                              void* d_out, int out_size, void* d_ws, size_t ws_size,
                              hipStream_t stream) {
    const float* pred = (const float*)d_in[0];   // (8,4,1,768,768) f32
    const int*   anno = (const int*)d_in[1];     // (8,1,768,768) i32
    float* out = (float*)d_out;

    int* counts = (int*)d_ws;                    // 32*CSLOT ints = 2 KB
    char* base  = (char*)d_ws + 4096;

    const size_t per_map = (size_t)PIX * 4 + (size_t)NT * 2 * W;  // labels + bcls
    size_t avail = (ws_size > 4096) ? ws_size - 4096 : 0;
    int K = (int)(avail / per_map);
    if (K > NMAPS) K = NMAPS;
    if (K < 1)     K = 1;    // best effort; needs ~2.6 MB min

    zero_counts_k<<<2, 256, 0, stream>>>(counts);

    for (int m0 = 0; m0 < NMAPS; m0 += K) {
        int nm = NMAPS - m0; if (nm > K) nm = K;
        int* labels         = (int*)base;
        unsigned char* bcls = (unsigned char*)(base + (size_t)K * PIX * 4);
        fused_k   <<<dim3(nm * NT), 256, 0, stream>>>(pred, anno, labels, bcls, counts, m0);
        boundary_k<<<dim3(nm * (NB * W / 256)), 256, 0, stream>>>(labels, bcls, counts, m0);
    }
    final_k<<<1, 1, 0, stream>>>(counts, out);
}

// Round 7
// 82.000 us; speedup vs baseline: 9.6675x; 1.0233x over previous
//
#include <hip/hip_runtime.h>

#define W     768
#define PIX   (768*768)
#define NMAPS 16            // 0..7 anno, 8..15 pred-argmax
#define TROWS 6
#define TPX   (TROWS*W)     // 4608 px per tile
#define NT    (768/TROWS)   // 128 tiles per map
#define NB    (NT-1)        // 127 tile boundaries per map
#define NSEG  (TPX/64)      // 72 wave-segments per tile (12 per row)
#define CSLOT 16            // ints per counter slot (64 B line)

// Labels are PACKED everywhere: (label<<2) | cls. Within a component all
// pixels share cls, and min over packed == min over label -> cls bits are
// invariant under atomicMin unions.

__device__ __forceinline__ int find_root_p(volatile int* L, int x) {
    int y = L[x] >> 2;
    while (y != x) { x = y; y = L[x] >> 2; }
    return x;
}

__device__ __forceinline__ void unite_p(int* L, int a, int b, int c) {
    volatile int* Lv = L;
    while (true) {
        a = find_root_p(Lv, a);
        b = find_root_p(Lv, b);
        if (a == b) return;
        if (a > b) { int t = a; a = b; b = t; }
        int old = atomicMin(&L[b], (a << 2) | c);
        if ((old >> 2) == b) return;
        b = old >> 2;
    }
}

// Packed global unite; true iff a link event occurred (two roots merged).
// Parents only decrease -> acyclic; each index loses rootness at most once,
// so #link events == #merges exactly, independent of atomic ordering.
__device__ __forceinline__ bool unite_gp(int* L, int a, int b, int c) {
    volatile int* Lv = L;
    while (true) {
        a = find_root_p(Lv, a);
        b = find_root_p(Lv, b);
        if (a == b) return false;
        if (a > b) { int t = a; a = b; b = t; }
        int old = atomicMin(&L[b], (a << 2) | c);
        if ((old >> 2) == b) return true;
        b = old >> 2;
    }
}

// ---------------- kernels ----------------

__global__ void zero_counts_k(int* counts) {
    int i = blockIdx.x * 256 + threadIdx.x;
    if (i < 32 * CSLOT) counts[i] = 0;
}

// One block per (map, 6-row tile). Wave-segment layout: 64 lanes = 64
// consecutive pixels of one row (12 segments/row). Phase A: decode cls,
// ballot-compute horizontal run starts -> initial labels pre-merge all
// horizontal runs. Phase B: segment stitches + per-run-pair vertical unions.
// Phase 3: resolve roots, count, write packed map-local labels.
__global__ __launch_bounds__(256) void fused_k(const float* __restrict__ pred,
                                               const int*   __restrict__ anno,
                                               int* __restrict__ labels,
                                               int* __restrict__ counts, int m0) {
    __shared__ int lab[TPX];               // 18 KB packed (label<<2)|cls
    __shared__ int s2[4], s3[4];

    int mc   = blockIdx.x / NT;
    int t    = blockIdx.x - mc * NT;
    int m    = m0 + mc;
    int tid  = threadIdx.x;
    int wid  = tid >> 6;
    int lane = tid & 63;

    unsigned long long cpack = 0;          // 2 bits/iteration, 18 iterations

    // ---- phase A: decode cls, run-start init (no LDS atomics) ----
    if (m < 8) {
        const int* src = anno + (size_t)m * PIX + (size_t)t * TPX;
        int it = 0;
        for (int seg = wid; seg < NSEG; seg += 4, ++it) {
            int px = seg * 64 + lane;
            int c  = src[px] & 3;
            cpack |= (unsigned long long)c << (2 * it);
            int cl = __shfl_up(c, 1);
            unsigned long long bm = __ballot(lane == 0 || c != cl);
            int ms = 63 - __clzll(bm & ((2ULL << lane) - 1));  // run start lane
            lab[px] = ((seg * 64 + ms) << 2) | c;
        }
    } else {
        const float* p0 = pred + (size_t)(m - 8) * 4 * PIX + (size_t)t * TPX;
        int it = 0;
        for (int seg = wid; seg < NSEG; seg += 4, ++it) {
            int px = seg * 64 + lane;
            float v0 = p0[px];
            float v1 = p0[(size_t)PIX + px];
            float v2 = p0[(size_t)2 * PIX + px];
            float v3 = p0[(size_t)3 * PIX + px];
            int c = 0; float bv = v0;       // strict '>' = first-max (jnp.argmax)
            if (v1 > bv) { bv = v1; c = 1; }
            if (v2 > bv) { bv = v2; c = 2; }
            if (v3 > bv) { bv = v3; c = 3; }
            cpack |= (unsigned long long)c << (2 * it);
            int cl = __shfl_up(c, 1);
            unsigned long long bm = __ballot(lane == 0 || c != cl);
            int ms = 63 - __clzll(bm & ((2ULL << lane) - 1));
            lab[px] = ((seg * 64 + ms) << 2) | c;
        }
    }
    __syncthreads();

    // ---- phase B: segment stitches + deduplicated vertical unions ----
    {
        int it = 0;
        for (int seg = wid; seg < NSEG; seg += 4, ++it) {
            int px = seg * 64 + lane;
            int c  = (int)((cpack >> (2 * it)) & 3);
            int cl = __shfl_up(c, 1);
            unsigned long long bA = __ballot(lane == 0 || c != cl);
            int mA = 63 - __clzll(bA & ((2ULL << lane) - 1));
            // stitch with previous segment in same row (cls bits are stable)
            if (lane == 0 && (seg % 12) != 0 && (c & 2)) {
                if ((lab[px - 1] & 3) == c) unite_p(lab, px - 1, px, c);
            }
            // vertical: union once per overlapping run pair, at first overlap col
            if (seg < NSEG - 12) {                    // row < TROWS-1 (wave-uniform)
                int cb = lab[px + W] & 3;
                int cbl = __shfl_up(cb, 1);
                unsigned long long bB = __ballot(lane == 0 || cb != cbl);
                int mB = 63 - __clzll(bB & ((2ULL << lane) - 1));
                int mx = mA > mB ? mA : mB;
                if ((c & 2) && cb == c && lane == mx)
                    unite_p(lab, px, px + W, c);
            }
        }
    }
    __syncthreads();

    // ---- phase 3: resolve roots, count, write packed map-local labels ----
    int c2 = 0, c3 = 0;
    int lbase = t * TPX;                       // map-local base of this tile
    int* gl = labels + (size_t)mc * PIX + lbase;
    {
        int it = 0;
        for (int seg = wid; seg < NSEG; seg += 4, ++it) {
            int px = seg * 64 + lane;
            int c  = (int)((cpack >> (2 * it)) & 3);
            int outv;
            if (c & 2) {
                int r = find_root_p(lab, px);
                if (r == px) { if (c == 2) c2++; else c3++; }
                outv = ((lbase + r) << 2) | c;
            } else {
                outv = ((lbase + px) << 2) | c;
            }
            gl[px] = outv;
        }
    }
    // reduce root counts -> one padded atomic per (block, class)
    for (int off = 32; off; off >>= 1) {
        c2 += __shfl_down(c2, off, 64);
        c3 += __shfl_down(c3, off, 64);
    }
    if (lane == 0) { s2[wid] = c2; s3[wid] = c3; }
    __syncthreads();
    if (tid == 0) {
        int t2 = s2[0] + s2[1] + s2[2] + s2[3];
        int t3 = s3[0] + s3[1] + s3[2] + s3[3];
        if (t2) atomicAdd(&counts[(m * 2 + 0) * CSLOT], t2);
        if (t3) atomicAdd(&counts[(m * 2 + 1) * CSLOT], t3);
    }
}

// Cross-tile boundary edges on packed labels; each successful root-link
// decrements that class's component count by exactly 1.
__global__ __launch_bounds__(256) void boundary_k(int* __restrict__ labels,
                                                  int* __restrict__ counts, int m0) {
    __shared__ int s2[4], s3[4];
    const int PERMAP = NB * W;                 // 97536 = 381 * 256 exactly
    int gid = blockIdx.x * 256 + threadIdx.x;
    int mc  = gid / PERMAP;
    int i   = gid - mc * PERMAP;
    int b   = i / W;
    int col = i - b * W;
    int m   = m0 + mc;

    int* L = labels + (size_t)mc * PIX;
    int p1 = b * TPX + (TROWS - 1) * W + col;  // tile b, last row
    int p2 = p1 + W;                           // tile b+1, row 0

    int m2 = 0, m3 = 0;
    int c1 = L[p1] & 3;
    int c2_ = L[p2] & 3;
    if (c1 == c2_ && (c1 & 2)) {
        if (unite_gp(L, p1, p2, c1)) { if (c1 == 2) m2++; else m3++; }
    }
    for (int off = 32; off; off >>= 1) {
        m2 += __shfl_down(m2, off, 64);
        m3 += __shfl_down(m3, off, 64);
    }
    int wid = threadIdx.x >> 6, lane = threadIdx.x & 63;
    if (lane == 0) { s2[wid] = m2; s3[wid] = m3; }
    __syncthreads();
    if (threadIdx.x == 0) {
        int t2 = s2[0] + s2[1] + s2[2] + s2[3];
        int t3 = s3[0] + s3[1] + s3[2] + s3[3];
        if (t2) atomicSub(&counts[(m * 2 + 0) * CSLOT], t2);
        if (t3) atomicSub(&counts[(m * 2 + 1) * CSLOT], t3);
    }
}

__global__ void final_k(const int* __restrict__ counts, float* __restrict__ out) {
    float s = 0.0f;
    for (int b = 0; b < 8; ++b) {
        float a2 = (float)counts[(b * 2 + 0) * CSLOT];
        float a3 = (float)counts[(b * 2 + 1) * CSLOT];
        float p2 = (float)counts[((8 + b) * 2 + 0) * CSLOT];
        float p3 = (float)counts[((8 + b) * 2 + 1) * CSLOT];
        float t2 = 1.0f - 2.0f * fminf(p2, a2) / (a2 + p2);
        float t3 = 1.0f - 2.0f * fminf(p3, a3) / (a3 + p3);
        s += t2 + t3;
    }
    out[0] = 0.5f * s;
}

// ---------------- launch ----------------

extern "C" void kernel_launch(void* const* d_in, const int* in_sizes, int n_in,
                              void* d_out, int out_size, void* d_ws, size_t ws_size,
                              hipStream_t stream) {
    const float* pred = (const float*)d_in[0];   // (8,4,1,768,768) f32
    const int*   anno = (const int*)d_in[1];     // (8,1,768,768) i32
    float* out = (float*)d_out;

    int* counts = (int*)d_ws;                    // 32*CSLOT ints = 2 KB
    char* base  = (char*)d_ws + 4096;

    const size_t per_map = (size_t)PIX * 4;      // packed labels only
    size_t avail = (ws_size > 4096) ? ws_size - 4096 : 0;
    int K = (int)(avail / per_map);
    if (K > NMAPS) K = NMAPS;
    if (K < 1)     K = 1;    // best effort; needs ~2.4 MB min

    zero_counts_k<<<2, 256, 0, stream>>>(counts);

    for (int m0 = 0; m0 < NMAPS; m0 += K) {
        int nm = NMAPS - m0; if (nm > K) nm = K;
        int* labels = (int*)base;
        fused_k   <<<dim3(nm * NT), 256, 0, stream>>>(pred, anno, labels, counts, m0);
        boundary_k<<<dim3(nm * (NB * W / 256)), 256, 0, stream>>>(labels, counts, m0);
    }
    final_k<<<1, 1, 0, stream>>>(counts, out);
}

// Round 8
// 69.688 us; speedup vs baseline: 11.3755x; 1.1767x over previous
//
#include <hip/hip_runtime.h>

#define W     768
#define PIX   (768*768)
#define NMAPS 16            // 0..7 anno, 8..15 pred-argmax
#define TROWS 6
#define TPX   (TROWS*W)     // 4608 px per tile
#define NT    (768/TROWS)   // 128 tiles per map
#define NB    (NT-1)        // 127 tile boundaries per map
#define NSEG  (TPX/64)      // 72 wave-segments per tile (12 per row)
#define NIT   (NSEG/4)      // 18 iterations per wave
#define CSLOT 16            // ints per counter slot (64 B line)

// Labels are PACKED everywhere: (label<<2) | cls. Within a component all
// pixels share cls, and min over packed == min over label -> cls bits are
// invariant under atomicMin unions.

__device__ __forceinline__ int find_root_p(volatile int* L, int x) {
    int y = L[x] >> 2;
    while (y != x) { x = y; y = L[x] >> 2; }
    return x;
}

__device__ __forceinline__ void unite_p(int* L, int a, int b, int c) {
    volatile int* Lv = L;
    while (true) {
        a = find_root_p(Lv, a);
        b = find_root_p(Lv, b);
        if (a == b) return;
        if (a > b) { int t = a; a = b; b = t; }
        int old = atomicMin(&L[b], (a << 2) | c);
        if ((old >> 2) == b) return;
        b = old >> 2;
    }
}

// Packed global unite; true iff a link event occurred (two roots merged).
// Parents only decrease -> acyclic; each index loses rootness at most once,
// so #link events == #merges exactly, independent of atomic ordering.
__device__ __forceinline__ bool unite_gp(int* L, int a, int b, int c) {
    volatile int* Lv = L;
    while (true) {
        a = find_root_p(Lv, a);
        b = find_root_p(Lv, b);
        if (a == b) return false;
        if (a > b) { int t = a; a = b; b = t; }
        int old = atomicMin(&L[b], (a << 2) | c);
        if ((old >> 2) == b) return true;
        b = old >> 2;
    }
}

// ---------------- kernels ----------------

__global__ void zero_counts_k(int* counts) {
    int i = blockIdx.x * 256 + threadIdx.x;
    if (i < 32 * CSLOT) counts[i] = 0;
}

// One block per (map, 6-row tile). Wave wid owns column-segments == wid
// (mod 4) of EVERY row, so vertical neighbors are same-wave: carry previous
// row's class/run-start in registers (3 strip slots, statically indexed via
// full unroll) and fire per-run-pair vertical unions inside phase A.
// Horizontal run init is free via ballot; only 66 cross-strip stitches
// remain after the barrier. Phase 3: resolve, count, write packed labels.
__global__ __launch_bounds__(256) void fused_k(const float* __restrict__ pred,
                                               const int*   __restrict__ anno,
                                               int* __restrict__ labels,
                                               int* __restrict__ counts, int m0) {
    __shared__ int lab[TPX];               // 18 KB packed (label<<2)|cls
    __shared__ int s2[4], s3[4];

    int mc   = blockIdx.x / NT;
    int t    = blockIdx.x - mc * NT;
    int m    = m0 + mc;
    int tid  = threadIdx.x;
    int wid  = tid >> 6;
    int lane = tid & 63;

    unsigned long long cpack = 0;          // 2 bits/iteration, NIT iterations
    int pc[3] = {0, 0, 0};                 // prev-row class per strip slot
    int pm[3] = {0, 0, 0};                 // prev-row run-start lane per slot

    const int*   asrc = anno + (size_t)m * PIX + (size_t)t * TPX;
    const float* psrc = pred + (size_t)(m < 8 ? 0 : (m - 8)) * 4 * PIX + (size_t)t * TPX;
    bool is_anno = (m < 8);

    // ---- phase A: decode cls, run-start init, in-register vertical unions ----
    #pragma unroll
    for (int it = 0; it < NIT; ++it) {
        int seg = wid + 4 * it;
        int px  = seg * 64 + lane;
        int c;
        if (is_anno) {
            c = asrc[px] & 3;
        } else {
            float v0 = psrc[px];
            float v1 = psrc[(size_t)PIX + px];
            float v2 = psrc[(size_t)2 * PIX + px];
            float v3 = psrc[(size_t)3 * PIX + px];
            c = 0; float bv = v0;           // strict '>' = first-max (jnp.argmax)
            if (v1 > bv) { bv = v1; c = 1; }
            if (v2 > bv) { bv = v2; c = 2; }
            if (v3 > bv) { bv = v3; c = 3; }
        }
        cpack |= (unsigned long long)c << (2 * it);
        int cl = __shfl_up(c, 1);
        unsigned long long bm = __ballot(lane == 0 || c != cl);
        int ms = 63 - __clzll(bm & ((2ULL << lane) - 1));   // run-start lane
        lab[px] = ((seg * 64 + ms) << 2) | c;
        // make this wave's label writes visible to its own ds reads below
        asm volatile("s_waitcnt lgkmcnt(0)" ::: "memory");
        const int sl = it % 3;              // static under full unroll
        if (it >= 3) {                      // row >= 1
            if ((c & 2) && c == pc[sl]) {
                int mx = ms > pm[sl] ? ms : pm[sl];
                if (lane == mx) unite_p(lab, px - W, px, c);   // wave-private strip
            }
        }
        pc[sl] = c; pm[sl] = ms;
    }
    __syncthreads();

    // ---- stitch phase: 66 cross-strip horizontal joins ----
    if (tid < TROWS * 11) {
        int row = tid / 11, j = tid % 11;
        int px  = row * W + (j + 1) * 64;
        int v = lab[px], c = v & 3;
        if (c & 2) {
            int vl = lab[px - 1];
            if ((vl & 3) == c) unite_p(lab, px - 1, px, c);
        }
    }
    __syncthreads();

    // ---- phase 3: resolve roots, count, write packed map-local labels ----
    int c2 = 0, c3 = 0;
    int lbase = t * TPX;                    // map-local base of this tile
    int* gl = labels + (size_t)mc * PIX + lbase;
    for (int it = 0; it < NIT; ++it) {
        int seg = wid + 4 * it;
        int px  = seg * 64 + lane;
        int c   = (int)((cpack >> (2 * it)) & 3);
        int outv;
        if (c & 2) {
            int r = find_root_p(lab, px);
            if (r == px) { if (c == 2) c2++; else c3++; }
            outv = ((lbase + r) << 2) | c;
        } else {
            outv = ((lbase + px) << 2) | c;
        }
        gl[px] = outv;
    }
    // reduce root counts -> one padded atomic per (block, class)
    for (int off = 32; off; off >>= 1) {
        c2 += __shfl_down(c2, off, 64);
        c3 += __shfl_down(c3, off, 64);
    }
    if (lane == 0) { s2[wid] = c2; s3[wid] = c3; }
    __syncthreads();
    if (tid == 0) {
        int t2 = s2[0] + s2[1] + s2[2] + s2[3];
        int t3 = s3[0] + s3[1] + s3[2] + s3[3];
        if (t2) atomicAdd(&counts[(m * 2 + 0) * CSLOT], t2);
        if (t3) atomicAdd(&counts[(m * 2 + 1) * CSLOT], t3);
    }
}

// Cross-tile boundary edges on packed labels; run-dedup via shfl (adjacent
// columns whose packed roots match in BOTH rows are provably redundant).
// Each successful root-link decrements that class's count by exactly 1.
__global__ __launch_bounds__(256) void boundary_k(int* __restrict__ labels,
                                                  int* __restrict__ counts, int m0) {
    __shared__ int s2[4], s3[4];
    const int PERMAP = NB * W;                 // 97536 = 381 * 256 exactly
    int gid = blockIdx.x * 256 + threadIdx.x;
    int mc  = gid / PERMAP;
    int i   = gid - mc * PERMAP;
    int b   = i / W;
    int col = i - b * W;
    int m   = m0 + mc;
    int lane = threadIdx.x & 63;

    int* L = labels + (size_t)mc * PIX;
    int p1 = b * TPX + (TROWS - 1) * W + col;  // tile b, last row
    int p2 = p1 + W;                           // tile b+1, row 0

    int m2 = 0, m3 = 0;
    int v1 = L[p1], v2 = L[p2];
    int c1 = v1 & 3, c2_ = v2 & 3;
    int pv1 = __shfl_up(v1, 1), pv2 = __shfl_up(v2, 1);
    bool match = (c1 == c2_) && (c1 & 2);
    bool redundant = (lane > 0) && (pv1 == v1) && (pv2 == v2);
    if (match && !redundant) {
        if (unite_gp(L, p1, p2, c1)) { if (c1 == 2) m2++; else m3++; }
    }
    for (int off = 32; off; off >>= 1) {
        m2 += __shfl_down(m2, off, 64);
        m3 += __shfl_down(m3, off, 64);
    }
    int wid = threadIdx.x >> 6;
    if (lane == 0) { s2[wid] = m2; s3[wid] = m3; }
    __syncthreads();
    if (threadIdx.x == 0) {
        int t2 = s2[0] + s2[1] + s2[2] + s2[3];
        int t3 = s3[0] + s3[1] + s3[2] + s3[3];
        if (t2) atomicSub(&counts[(m * 2 + 0) * CSLOT], t2);
        if (t3) atomicSub(&counts[(m * 2 + 1) * CSLOT], t3);
    }
}

__global__ void final_k(const int* __restrict__ counts, float* __restrict__ out) {
    float s = 0.0f;
    for (int b = 0; b < 8; ++b) {
        float a2 = (float)counts[(b * 2 + 0) * CSLOT];
        float a3 = (float)counts[(b * 2 + 1) * CSLOT];
        float p2 = (float)counts[((8 + b) * 2 + 0) * CSLOT];
        float p3 = (float)counts[((8 + b) * 2 + 1) * CSLOT];
        float t2 = 1.0f - 2.0f * fminf(p2, a2) / (a2 + p2);
        float t3 = 1.0f - 2.0f * fminf(p3, a3) / (a3 + p3);
        s += t2 + t3;
    }
    out[0] = 0.5f * s;
}

// ---------------- launch ----------------

extern "C" void kernel_launch(void* const* d_in, const int* in_sizes, int n_in,
                              void* d_out, int out_size, void* d_ws, size_t ws_size,
                              hipStream_t stream) {
    const float* pred = (const float*)d_in[0];   // (8,4,1,768,768) f32
    const int*   anno = (const int*)d_in[1];     // (8,1,768,768) i32
    float* out = (float*)d_out;

    int* counts = (int*)d_ws;                    // 32*CSLOT ints = 2 KB
    char* base  = (char*)d_ws + 4096;

    const size_t per_map = (size_t)PIX * 4;      // packed labels only
    size_t avail = (ws_size > 4096) ? ws_size - 4096 : 0;
    int K = (int)(avail / per_map);
    if (K > NMAPS) K = NMAPS;
    if (K < 1)     K = 1;    // best effort; needs ~2.4 MB min

    zero_counts_k<<<2, 256, 0, stream>>>(counts);

    for (int m0 = 0; m0 < NMAPS; m0 += K) {
        int nm = NMAPS - m0; if (nm > K) nm = K;
        int* labels = (int*)base;
        fused_k   <<<dim3(nm * NT), 256, 0, stream>>>(pred, anno, labels, counts, m0);
        boundary_k<<<dim3(nm * (NB * W / 256)), 256, 0, stream>>>(labels, counts, m0);
    }
    final_k<<<1, 1, 0, stream>>>(counts, out);
}

// Round 9
// 59.007 us; speedup vs baseline: 13.4345x; 1.1810x over previous
//
#include <hip/hip_runtime.h>

#define W     768
#define PIX   (768*768)
#define NMAPS 16            // 0..7 anno, 8..15 pred-argmax
#define TROWS 6
#define TPX   (TROWS*W)     // 4608 px per tile
#define NT    (768/TROWS)   // 128 tiles per map
#define NB    (NT-1)        // 127 tile boundaries per map
#define NSEG  (TPX/64)      // 72 wave-segments per tile (12 per row)
#define NIT   (NSEG/4)      // 18 iterations per wave
#define CSLOT 16            // ints per counter slot (64 B line)

// Labels are PACKED everywhere: (label<<2) | cls. Within a component all
// pixels share cls, and min over packed == min over label -> cls bits are
// invariant under atomicMin unions.

__device__ __forceinline__ int find_root_p(volatile int* L, int x) {
    int y = L[x] >> 2;
    while (y != x) { x = y; y = L[x] >> 2; }
    return x;
}

__device__ __forceinline__ void unite_p(int* L, int a, int b, int c) {
    volatile int* Lv = L;
    while (true) {
        a = find_root_p(Lv, a);
        b = find_root_p(Lv, b);
        if (a == b) return;
        if (a > b) { int t = a; a = b; b = t; }
        int old = atomicMin(&L[b], (a << 2) | c);
        if ((old >> 2) == b) return;
        b = old >> 2;
    }
}

// Packed global unite; true iff a link event occurred (two roots merged).
// Parents only decrease -> acyclic; each index loses rootness at most once,
// so #link events == #merges exactly, independent of atomic ordering.
__device__ __forceinline__ bool unite_gp(int* L, int a, int b, int c) {
    volatile int* Lv = L;
    while (true) {
        a = find_root_p(Lv, a);
        b = find_root_p(Lv, b);
        if (a == b) return false;
        if (a > b) { int t = a; a = b; b = t; }
        int old = atomicMin(&L[b], (a << 2) | c);
        if ((old >> 2) == b) return true;
        b = old >> 2;
    }
}

// ---------------- kernels ----------------

// One block per (map, 6-row tile). Wave wid owns column-segments == wid
// (mod 4) of EVERY row -> vertical neighbors are same-wave; per-run-pair
// vertical unions fire inside phase A from register-carried prev-row state.
// All pre-barrier LDS deps are same-wave: DS ops of a wave execute in issue
// order, so no explicit lgkmcnt is needed (volatile/atomic stops compiler
// reordering). Phase 3 writes SPARSE global labels: only tile-boundary rows
// (compressed to roots -> global chains start depth-1) plus root self-
// pointers (chain interiors under atomicMin-linking are always ex-roots).
__global__ __launch_bounds__(256) void fused_k(const float* __restrict__ pred,
                                               const int*   __restrict__ anno,
                                               int* __restrict__ labels,
                                               int* __restrict__ counts, int m0) {
    __shared__ int lab[TPX];               // 18 KB packed (label<<2)|cls
    __shared__ int s2[4], s3[4];

    int mc   = blockIdx.x / NT;
    int t    = blockIdx.x - mc * NT;
    int m    = m0 + mc;
    int tid  = threadIdx.x;
    int wid  = tid >> 6;
    int lane = tid & 63;

    int pc[3] = {0, 0, 0};                 // prev-row class per strip slot
    int pm[3] = {0, 0, 0};                 // prev-row run-start lane per slot

    const int*   asrc = anno + (size_t)m * PIX + (size_t)t * TPX;
    const float* psrc = pred + (size_t)(m < 8 ? 0 : (m - 8)) * 4 * PIX + (size_t)t * TPX;
    bool is_anno = (m < 8);

    // ---- phase A: decode cls, run-start init, in-register vertical unions ----
    #pragma unroll
    for (int it = 0; it < NIT; ++it) {
        int seg = wid + 4 * it;
        int px  = seg * 64 + lane;
        int c;
        if (is_anno) {
            c = asrc[px] & 3;
        } else {
            float v0 = psrc[px];
            float v1 = psrc[(size_t)PIX + px];
            float v2 = psrc[(size_t)2 * PIX + px];
            float v3 = psrc[(size_t)3 * PIX + px];
            c = 0; float bv = v0;           // strict '>' = first-max (jnp.argmax)
            if (v1 > bv) { bv = v1; c = 1; }
            if (v2 > bv) { bv = v2; c = 2; }
            if (v3 > bv) { bv = v3; c = 3; }
        }
        int cl = __shfl_up(c, 1);
        unsigned long long bm = __ballot(lane == 0 || c != cl);
        int ms = 63 - __clzll(bm & ((2ULL << lane) - 1));   // run-start lane
        lab[px] = ((seg * 64 + ms) << 2) | c;
        const int sl = it % 3;              // static under full unroll
        if (it >= 3) {                      // row >= 1: wave-private strip union
            if ((c & 2) && c == pc[sl]) {
                int mx = ms > pm[sl] ? ms : pm[sl];
                if (lane == mx) unite_p(lab, px - W, px, c);
            }
        }
        pc[sl] = c; pm[sl] = ms;
    }
    __syncthreads();

    // ---- stitch phase: 66 cross-strip horizontal joins ----
    if (tid < TROWS * 11) {
        int row = tid / 11, j = tid % 11;
        int px  = row * W + (j + 1) * 64;
        int v = lab[px], c = v & 3;
        if (c & 2) {
            int vl = lab[px - 1];
            if ((vl & 3) == c) unite_p(lab, px - 1, px, c);
        }
    }
    __syncthreads();

    // ---- phase 3: count roots (1 read, no find), sparse label writes ----
    int c2 = 0, c3 = 0;
    int lbase = t * TPX;                    // map-local base of this tile
    int* gl = labels + (size_t)mc * PIX + lbase;
    #pragma unroll
    for (int it = 0; it < NIT; ++it) {
        int seg = wid + 4 * it;
        int px  = seg * 64 + lane;
        int v   = lab[px];
        int c   = v & 3;
        bool incls  = (c & 2) != 0;
        bool isroot = incls && ((v >> 2) == px);
        if (isroot) { if (c == 2) c2++; else c3++; }
        if (it < 3 || it >= NIT - 3) {      // tile rows 0 and TROWS-1
            int outv;
            if (incls) {
                int r = find_root_p(lab, px);
                outv = ((lbase + r) << 2) | c;
            } else {
                outv = ((lbase + px) << 2) | c;
            }
            gl[px] = outv;
        } else if (isroot) {
            gl[px] = ((lbase + px) << 2) | c;   // self-pointer for chain interiors
        }
    }
    // reduce root counts -> one padded atomic per (block, class)
    for (int off = 32; off; off >>= 1) {
        c2 += __shfl_down(c2, off, 64);
        c3 += __shfl_down(c3, off, 64);
    }
    if (lane == 0) { s2[wid] = c2; s3[wid] = c3; }
    __syncthreads();
    if (tid == 0) {
        int t2 = s2[0] + s2[1] + s2[2] + s2[3];
        int t3 = s3[0] + s3[1] + s3[2] + s3[3];
        if (t2) atomicAdd(&counts[(m * 2 + 0) * CSLOT], t2);
        if (t3) atomicAdd(&counts[(m * 2 + 1) * CSLOT], t3);
    }
}

// Cross-tile boundary edges on packed labels, 2 columns per thread (int2).
// Run-dedup: skip a union when the packed-value pair equals the previous
// column's pair (provably same run pair; dedup is an optimization only --
// duplicate unions are idempotent and count only real merges).
// blockIdx.y = map -> counts index is block-uniform.
__global__ __launch_bounds__(256) void boundary_k(int* __restrict__ labels,
                                                  int* __restrict__ counts, int m0) {
    __shared__ int s2[4], s3[4];
    const int HM = NB * (W / 2);               // 48768 col-pairs per map
    int i    = blockIdx.x * 256 + threadIdx.x;
    int mc   = blockIdx.y;
    int m    = m0 + mc;
    int lane = threadIdx.x & 63;

    int m2 = 0, m3 = 0;
    if (i < HM) {
        int b   = i / (W / 2);
        int col = (i - b * (W / 2)) * 2;
        int* L  = labels + (size_t)mc * PIX;
        int p1  = b * TPX + (TROWS - 1) * W + col;   // tile b, last row
        int p2  = p1 + W;                            // tile b+1, row 0
        int2 va = *(const int2*)&L[p1];
        int2 vb = *(const int2*)&L[p2];
        int pay = __shfl_up(va.y, 1), pby = __shfl_up(vb.y, 1);
        int c0 = va.x & 3;
        if (c0 == (vb.x & 3) && (c0 & 2)) {
            bool red = (lane > 0) && (pay == va.x) && (pby == vb.x);
            if (!red && unite_gp(L, p1, p2, c0)) { if (c0 == 2) m2++; else m3++; }
        }
        int c1 = va.y & 3;
        if (c1 == (vb.y & 3) && (c1 & 2)) {
            bool red = (va.x == va.y) && (vb.x == vb.y);
            if (!red && unite_gp(L, p1 + 1, p2 + 1, c1)) { if (c1 == 2) m2++; else m3++; }
        }
    }
    for (int off = 32; off; off >>= 1) {
        m2 += __shfl_down(m2, off, 64);
        m3 += __shfl_down(m3, off, 64);
    }
    int wid = threadIdx.x >> 6;
    if (lane == 0) { s2[wid] = m2; s3[wid] = m3; }
    __syncthreads();
    if (threadIdx.x == 0) {
        int t2 = s2[0] + s2[1] + s2[2] + s2[3];
        int t3 = s3[0] + s3[1] + s3[2] + s3[3];
        if (t2) atomicSub(&counts[(m * 2 + 0) * CSLOT], t2);
        if (t3) atomicSub(&counts[(m * 2 + 1) * CSLOT], t3);
    }
}

__global__ void final_k(const int* __restrict__ counts, float* __restrict__ out) {
    float s = 0.0f;
    for (int b = 0; b < 8; ++b) {
        float a2 = (float)counts[(b * 2 + 0) * CSLOT];
        float a3 = (float)counts[(b * 2 + 1) * CSLOT];
        float p2 = (float)counts[((8 + b) * 2 + 0) * CSLOT];
        float p3 = (float)counts[((8 + b) * 2 + 1) * CSLOT];
        float t2 = 1.0f - 2.0f * fminf(p2, a2) / (a2 + p2);
        float t3 = 1.0f - 2.0f * fminf(p3, a3) / (a3 + p3);
        s += t2 + t3;
    }
    out[0] = 0.5f * s;
}

// ---------------- launch ----------------

extern "C" void kernel_launch(void* const* d_in, const int* in_sizes, int n_in,
                              void* d_out, int out_size, void* d_ws, size_t ws_size,
                              hipStream_t stream) {
    const float* pred = (const float*)d_in[0];   // (8,4,1,768,768) f32
    const int*   anno = (const int*)d_in[1];     // (8,1,768,768) i32
    float* out = (float*)d_out;

    int* counts = (int*)d_ws;                    // 32*CSLOT ints = 2 KB
    char* base  = (char*)d_ws + 4096;

    const size_t per_map = (size_t)PIX * 4;      // packed labels only
    size_t avail = (ws_size > 4096) ? ws_size - 4096 : 0;
    int K = (int)(avail / per_map);
    if (K > NMAPS) K = NMAPS;
    if (K < 1)     K = 1;    // best effort; needs ~2.4 MB min

    hipMemsetAsync(counts, 0, 32 * CSLOT * sizeof(int), stream);

    const int HM = NB * (W / 2);                 // 48768 col-pairs per map
    for (int m0 = 0; m0 < NMAPS; m0 += K) {
        int nm = NMAPS - m0; if (nm > K) nm = K;
        int* labels = (int*)base;
        fused_k   <<<dim3(nm * NT), 256, 0, stream>>>(pred, anno, labels, counts, m0);
        boundary_k<<<dim3((HM + 255) / 256, nm), 256, 0, stream>>>(labels, counts, m0);
    }
    final_k<<<1, 1, 0, stream>>>(counts, out);
}